// Round 1
// baseline (219.193 us; speedup 1.0000x reference)
//
#include <hip/hip_runtime.h>

#define MAXOBJ 65536
#define KSLOTS 8
#define DFEAT 256

// ws layout: [0, MAXOBJ) ints: slot chosen for object (or -1 if untouched)
//            [MAXOBJ, 2*MAXOBJ) ints: source row m in features for that object

__global__ void init_slots_kernel(int* __restrict__ slots, int n) {
    int i = blockIdx.x * blockDim.x + threadIdx.x;
    if (i < n) slots[i] = -1;
}

__global__ void slot_compute_kernel(const float* __restrict__ capture_poses,
                                    const int* __restrict__ slot_count,
                                    const int* __restrict__ object_indices,
                                    const float* __restrict__ camera_pose,
                                    int* __restrict__ slots,
                                    int* __restrict__ srcs,
                                    int M) {
    int m = blockIdx.x * blockDim.x + threadIdx.x;
    if (m >= M) return;
    int obj = object_indices[m];

    float Rc[3][3], tc[3];
#pragma unroll
    for (int i = 0; i < 3; i++) {
        Rc[i][0] = camera_pose[i * 4 + 0];
        Rc[i][1] = camera_pose[i * 4 + 1];
        Rc[i][2] = camera_pose[i * 4 + 2];
        tc[i]    = camera_pose[i * 4 + 3];
    }

    int cnt = slot_count[obj];
    const float* ps = capture_poses + (size_t)obj * (KSLOTS * 16);

    float best = 3.4e38f;
    int bestk = 0;
#pragma unroll
    for (int k = 0; k < KSLOTS; k++) {
        const float* p = ps + k * 16;
        float rot = 0.f;
#pragma unroll
        for (int i = 0; i < 3; i++) {
#pragma unroll
            for (int l = 0; l < 3; l++) {
                // R_diff[i][l] = sum_j Rc[i][j] * Rs[l][j]
                float v = Rc[i][0] * p[l * 4 + 0] + Rc[i][1] * p[l * 4 + 1] + Rc[i][2] * p[l * 4 + 2];
                v -= (i == l) ? 1.f : 0.f;
                rot += v * v;
            }
        }
        float tx = tc[0] - p[3];
        float ty = tc[1] - p[7];
        float tz = tc[2] - p[11];
        float delta = sqrtf(rot) + sqrtf(tx * tx + ty * ty + tz * tz);
        if (delta < best) { best = delta; bestk = k; }  // strict <: first-min tie-break like jnp.argmin
    }

    int fill = (cnt < KSLOTS) ? 1 : 0;
    int slot = fill ? cnt : bestk;
    slots[obj] = slot;
    srcs[obj] = m;
}

__global__ void small_outputs_kernel(const unsigned char* __restrict__ slot_filled,
                                     const int* __restrict__ slot_count,
                                     const int* __restrict__ slots,
                                     float* __restrict__ filled_out,
                                     float* __restrict__ count_out) {
    int obj = blockIdx.x * blockDim.x + threadIdx.x;
    if (obj >= MAXOBJ) return;
    int slot = slots[obj];
    int cnt = slot_count[obj];
    int fill = (slot >= 0 && cnt < KSLOTS) ? 1 : 0;
    count_out[obj] = (float)(cnt + fill);
#pragma unroll
    for (int k = 0; k < KSLOTS; k++) {
        int was = slot_filled[obj * KSLOTS + k] != 0;
        filled_out[obj * KSLOTS + k] = (was || k == slot) ? 1.0f : 0.0f;
    }
}

// One float4 per thread; a wave64 covers exactly one 256-float row -> replace
// branch is wave-uniform.
__global__ void mem_copy_kernel(const float4* __restrict__ memory,
                                const float4* __restrict__ features,
                                const int* __restrict__ slots,
                                const int* __restrict__ srcs,
                                float4* __restrict__ out) {
    int i = blockIdx.x * blockDim.x + threadIdx.x;  // float4 index, total 33554432
    if (i >= MAXOBJ * KSLOTS * (DFEAT / 4)) return;
    int elem = i * 4;
    int obj = elem >> 11;            // 2048 floats per object
    int k   = (elem >> 8) & 7;       // 256 floats per row
    int d4  = i & (DFEAT / 4 - 1);
    int slot = slots[obj];
    float4 v;
    if (k == slot) {
        v = features[(size_t)srcs[obj] * (DFEAT / 4) + d4];
    } else {
        v = memory[i];
    }
    out[i] = v;
}

__global__ void pose_copy_kernel(const float4* __restrict__ capture_poses,
                                 const float4* __restrict__ camera_pose,
                                 const int* __restrict__ slots,
                                 float4* __restrict__ out) {
    int i = blockIdx.x * blockDim.x + threadIdx.x;  // float4 index, total 2097152
    if (i >= MAXOBJ * KSLOTS * 4) return;
    int elem = i * 4;
    int obj = elem >> 7;         // 128 floats per object
    int k   = (elem >> 4) & 7;   // 16 floats per pose
    int r4  = i & 3;
    int slot = slots[obj];
    float4 v = (k == slot) ? camera_pose[r4] : capture_poses[i];
    out[i] = v;
}

extern "C" void kernel_launch(void* const* d_in, const int* in_sizes, int n_in,
                              void* d_out, int out_size, void* d_ws, size_t ws_size,
                              hipStream_t stream) {
    const float*         memory        = (const float*)d_in[0];
    const float*         capture_poses = (const float*)d_in[1];
    const unsigned char* slot_filled   = (const unsigned char*)d_in[2];
    const int*           slot_count    = (const int*)d_in[3];
    const int*           object_indices= (const int*)d_in[4];
    const float*         features      = (const float*)d_in[5];
    const float*         camera_pose   = (const float*)d_in[6];
    const int M = in_sizes[4];

    float* out = (float*)d_out;
    float* mem_out    = out;
    float* poses_out  = out + (size_t)MAXOBJ * KSLOTS * DFEAT;                  // 134217728
    float* filled_out = poses_out + (size_t)MAXOBJ * KSLOTS * 16;               // +8388608
    float* count_out  = filled_out + (size_t)MAXOBJ * KSLOTS;                   // +524288

    int* slots = (int*)d_ws;
    int* srcs  = slots + MAXOBJ;

    const int B = 256;

    init_slots_kernel<<<(MAXOBJ + B - 1) / B, B, 0, stream>>>(slots, MAXOBJ);

    slot_compute_kernel<<<(M + B - 1) / B, B, 0, stream>>>(
        capture_poses, slot_count, object_indices, camera_pose, slots, srcs, M);

    small_outputs_kernel<<<(MAXOBJ + B - 1) / B, B, 0, stream>>>(
        slot_filled, slot_count, slots, filled_out, count_out);

    const int mem4 = MAXOBJ * KSLOTS * (DFEAT / 4);   // 33554432
    mem_copy_kernel<<<(mem4 + B - 1) / B, B, 0, stream>>>(
        (const float4*)memory, (const float4*)features, slots, srcs, (float4*)mem_out);

    const int pose4 = MAXOBJ * KSLOTS * 4;            // 2097152
    pose_copy_kernel<<<(pose4 + B - 1) / B, B, 0, stream>>>(
        (const float4*)capture_poses, (const float4*)camera_pose, slots, (float4*)poses_out);
}

// Round 2
// 209.903 us; speedup vs baseline: 1.0443x; 1.0443x over previous
//
#include <hip/hip_runtime.h>

#define MAXOBJ 65536
#define KSLOTS 8
#define DFEAT 256

typedef float f32x4 __attribute__((ext_vector_type(4)));

// ws layout: [0, MAXOBJ) ints: slot chosen for object (or -1 if untouched)
//            [MAXOBJ, 2*MAXOBJ) ints: source row m in features for that object

__global__ void init_slots_kernel(int* __restrict__ slots, int n) {
    int i = blockIdx.x * blockDim.x + threadIdx.x;
    if (i < n) slots[i] = -1;
}

__global__ void slot_compute_kernel(const float* __restrict__ capture_poses,
                                    const int* __restrict__ slot_count,
                                    const int* __restrict__ object_indices,
                                    const float* __restrict__ camera_pose,
                                    int* __restrict__ slots,
                                    int* __restrict__ srcs,
                                    int M) {
    int m = blockIdx.x * blockDim.x + threadIdx.x;
    if (m >= M) return;
    int obj = object_indices[m];

    float Rc[3][3], tc[3];
#pragma unroll
    for (int i = 0; i < 3; i++) {
        Rc[i][0] = camera_pose[i * 4 + 0];
        Rc[i][1] = camera_pose[i * 4 + 1];
        Rc[i][2] = camera_pose[i * 4 + 2];
        tc[i]    = camera_pose[i * 4 + 3];
    }

    int cnt = slot_count[obj];
    const float* ps = capture_poses + (size_t)obj * (KSLOTS * 16);

    float best = 3.4e38f;
    int bestk = 0;
#pragma unroll
    for (int k = 0; k < KSLOTS; k++) {
        const float* p = ps + k * 16;
        float rot = 0.f;
#pragma unroll
        for (int i = 0; i < 3; i++) {
#pragma unroll
            for (int l = 0; l < 3; l++) {
                // R_diff[i][l] = sum_j Rc[i][j] * Rs[l][j]
                float v = Rc[i][0] * p[l * 4 + 0] + Rc[i][1] * p[l * 4 + 1] + Rc[i][2] * p[l * 4 + 2];
                v -= (i == l) ? 1.f : 0.f;
                rot += v * v;
            }
        }
        float tx = tc[0] - p[3];
        float ty = tc[1] - p[7];
        float tz = tc[2] - p[11];
        float delta = sqrtf(rot) + sqrtf(tx * tx + ty * ty + tz * tz);
        if (delta < best) { best = delta; bestk = k; }  // strict <: first-min tie-break like jnp.argmin
    }

    int fill = (cnt < KSLOTS) ? 1 : 0;
    int slot = fill ? cnt : bestk;
    slots[obj] = slot;
    srcs[obj] = m;
}

// One block (256 threads) = one object. All control data (slot, src, cnt) is
// block-uniform -> scalar loads, wave-uniform branches.
// Thread t copies float4 indices obj*512 + t and obj*512 + 256 + t:
//   pass 1: wave w (=t/64) covers feature-row w      (rows 0..3)
//   pass 2: wave w covers feature-row 4+w            (rows 4..7)
// Lanes t<32 additionally copy the 8 stored poses (32 float4), lanes 64..71
// write slot_filled, lane 96 writes slot_count.
__global__ void fused_copy_kernel(const f32x4* __restrict__ memory,
                                  const f32x4* __restrict__ features,
                                  const f32x4* __restrict__ capture_poses,
                                  const f32x4* __restrict__ camera_pose,
                                  const unsigned char* __restrict__ slot_filled,
                                  const int* __restrict__ slot_count,
                                  const int* __restrict__ slots,
                                  const int* __restrict__ srcs,
                                  f32x4* __restrict__ mem_out,
                                  f32x4* __restrict__ poses_out,
                                  float* __restrict__ filled_out,
                                  float* __restrict__ count_out) {
    const int obj = blockIdx.x;
    const int t = threadIdx.x;
    const int slot = slots[obj];      // uniform -> s_load
    const int src  = srcs[obj];       // uniform -> s_load

    const size_t base = (size_t)obj * (KSLOTS * DFEAT / 4);  // 512 f4 per object
    const int d4 = t & 63;

    // pass 1: rows 0..3
    {
        const int k = t >> 6;
        f32x4 v;
        if (k == slot) {
            v = features[(size_t)src * (DFEAT / 4) + d4];
        } else {
            v = __builtin_nontemporal_load(&memory[base + t]);
        }
        __builtin_nontemporal_store(v, &mem_out[base + t]);
    }
    // pass 2: rows 4..7
    {
        const int k = 4 + (t >> 6);
        f32x4 v;
        if (k == slot) {
            v = features[(size_t)src * (DFEAT / 4) + d4];
        } else {
            v = __builtin_nontemporal_load(&memory[base + 256 + t]);
        }
        __builtin_nontemporal_store(v, &mem_out[base + 256 + t]);
    }

    // poses: 32 float4 per object, lanes 0..31
    if (t < 32) {
        const int k  = t >> 2;   // pose row 0..7
        const int r4 = t & 3;    // row of the 4x4 matrix
        const size_t pbase = (size_t)obj * (KSLOTS * 16 / 4);
        f32x4 v = (k == slot) ? camera_pose[r4] : capture_poses[pbase + t];
        poses_out[pbase + t] = v;
    }

    // slot_filled: 8 floats, lanes 64..71 (second wave, keeps wave 0 clean)
    if (t >= 64 && t < 64 + KSLOTS) {
        const int k = t - 64;
        int was = slot_filled[obj * KSLOTS + k] != 0;
        filled_out[obj * KSLOTS + k] = (was || k == slot) ? 1.0f : 0.0f;
    }

    // slot_count: lane 96
    if (t == 96) {
        int cnt = slot_count[obj];
        int fill = (slot >= 0 && cnt < KSLOTS) ? 1 : 0;
        count_out[obj] = (float)(cnt + fill);
    }
}

extern "C" void kernel_launch(void* const* d_in, const int* in_sizes, int n_in,
                              void* d_out, int out_size, void* d_ws, size_t ws_size,
                              hipStream_t stream) {
    const float*         memory        = (const float*)d_in[0];
    const float*         capture_poses = (const float*)d_in[1];
    const unsigned char* slot_filled   = (const unsigned char*)d_in[2];
    const int*           slot_count    = (const int*)d_in[3];
    const int*           object_indices= (const int*)d_in[4];
    const float*         features      = (const float*)d_in[5];
    const float*         camera_pose   = (const float*)d_in[6];
    const int M = in_sizes[4];

    float* out = (float*)d_out;
    float* mem_out    = out;
    float* poses_out  = out + (size_t)MAXOBJ * KSLOTS * DFEAT;                  // 134217728
    float* filled_out = poses_out + (size_t)MAXOBJ * KSLOTS * 16;               // +8388608
    float* count_out  = filled_out + (size_t)MAXOBJ * KSLOTS;                   // +524288

    int* slots = (int*)d_ws;
    int* srcs  = slots + MAXOBJ;

    const int B = 256;

    init_slots_kernel<<<(MAXOBJ + B - 1) / B, B, 0, stream>>>(slots, MAXOBJ);

    slot_compute_kernel<<<(M + B - 1) / B, B, 0, stream>>>(
        capture_poses, slot_count, object_indices, camera_pose, slots, srcs, M);

    fused_copy_kernel<<<MAXOBJ, B, 0, stream>>>(
        (const f32x4*)memory, (const f32x4*)features,
        (const f32x4*)capture_poses, (const f32x4*)camera_pose,
        slot_filled, slot_count, slots, srcs,
        (f32x4*)mem_out, (f32x4*)poses_out, filled_out, count_out);
}

// Round 3
// 190.683 us; speedup vs baseline: 1.1495x; 1.1008x over previous
//
#include <hip/hip_runtime.h>

#define MAXOBJ 65536
#define KSLOTS 8
#define DFEAT 256

typedef float f32x4 __attribute__((ext_vector_type(4)));

// ws layout: [0, MAXOBJ) ints: source row m in features for that object, or -1

__global__ void init_srcs_kernel(int* __restrict__ srcs, int n) {
    int i = blockIdx.x * blockDim.x + threadIdx.x;
    if (i < n) srcs[i] = -1;
}

__global__ void scatter_srcs_kernel(const int* __restrict__ object_indices,
                                    int* __restrict__ srcs, int M) {
    int m = blockIdx.x * blockDim.x + threadIdx.x;
    if (m < M) srcs[object_indices[m]] = m;
}

// One block (256 threads) = one object.
// Wave 0 lanes 0..31: load the 8 stored poses (4 lanes x f32x4 rows each),
// compute the 8 pose deltas (4-lane shuffle reduce), argmin over k (3x
// shfl_xor with lowest-k tie-break == jnp.argmin first-min), derive the
// target slot, write poses_out / filled_out / count_out, broadcast slot via
// LDS. All 256 threads then stream-copy the 8x256-float feature rows with
// the chosen row replaced by `features[src]`. All control data is
// block-uniform -> scalar loads, wave-uniform branches.
__global__ void fused_kernel(const f32x4* __restrict__ memory,
                             const f32x4* __restrict__ features,
                             const f32x4* __restrict__ capture_poses,
                             const float* __restrict__ camera_pose,
                             const unsigned char* __restrict__ slot_filled,
                             const int* __restrict__ slot_count,
                             const int* __restrict__ srcs,
                             f32x4* __restrict__ mem_out,
                             f32x4* __restrict__ poses_out,
                             float* __restrict__ filled_out,
                             float* __restrict__ count_out) {
    const int obj = blockIdx.x;
    const int t = threadIdx.x;
    const int src = srcs[obj];        // uniform -> s_load
    const int d4 = t & 63;

    // Issue the features-row load early; latency hides under pose work.
    f32x4 feat = {0.f, 0.f, 0.f, 0.f};
    if (src >= 0) feat = features[(size_t)src * (DFEAT / 4) + d4];

    __shared__ int s_slot;

    if (t < 32) {
        const int k  = t >> 2;   // pose 0..7
        const int r4 = t & 3;    // row of the 4x4
        const size_t pbase = (size_t)obj * (KSLOTS * 16 / 4);
        f32x4 pv = capture_poses[pbase + t];

        // camera pose rows (uniform scalar loads)
        float Rc00 = camera_pose[0],  Rc01 = camera_pose[1],  Rc02 = camera_pose[2];
        float Rc10 = camera_pose[4],  Rc11 = camera_pose[5],  Rc12 = camera_pose[6];
        float Rc20 = camera_pose[8],  Rc21 = camera_pose[9],  Rc22 = camera_pose[10];
        float tc0 = camera_pose[3], tc1 = camera_pose[7], tc2 = camera_pose[11];

        // per-lane partial: stored-rotation row l = r4 (cols pv.x..z),
        // stored translation element = pv.w
        float rot_part = 0.f, tr_part = 0.f;
        if (r4 < 3) {
            float v0 = Rc00 * pv.x + Rc01 * pv.y + Rc02 * pv.z - (r4 == 0 ? 1.f : 0.f);
            float v1 = Rc10 * pv.x + Rc11 * pv.y + Rc12 * pv.z - (r4 == 1 ? 1.f : 0.f);
            float v2 = Rc20 * pv.x + Rc21 * pv.y + Rc22 * pv.z - (r4 == 2 ? 1.f : 0.f);
            rot_part = v0 * v0 + v1 * v1 + v2 * v2;
            float tcur = (r4 == 0) ? tc0 : (r4 == 1) ? tc1 : tc2;
            float dt = tcur - pv.w;
            tr_part = dt * dt;
        }
        // reduce over the 4 lanes of this pose group
        rot_part += __shfl_xor(rot_part, 1);
        tr_part  += __shfl_xor(tr_part, 1);
        rot_part += __shfl_xor(rot_part, 2);
        tr_part  += __shfl_xor(tr_part, 2);
        float delta = sqrtf(rot_part) + sqrtf(tr_part);

        // argmin over the 8 pose groups (lanes differ only in bits 2..4)
        int bestk = k;
        float bestd = delta;
#pragma unroll
        for (int mask = 4; mask <= 16; mask <<= 1) {
            float od = __shfl_xor(bestd, mask);
            int   ok = __shfl_xor(bestk, mask);
            if (od < bestd || (od == bestd && ok < bestk)) { bestd = od; bestk = ok; }
        }

        const int cnt = slot_count[obj];   // uniform -> s_load
        const int fill = (cnt < KSLOTS) ? 1 : 0;
        const int slot = (src < 0) ? -1 : (fill ? cnt : bestk);

        if (t == 0) {
            s_slot = slot;
            count_out[obj] = (float)(cnt + ((src >= 0) ? fill : 0));
        }
        if (t < KSLOTS) {
            int was = slot_filled[obj * KSLOTS + t] != 0;
            filled_out[obj * KSLOTS + t] = (was || t == slot) ? 1.0f : 0.0f;
        }
        // pose copy: this lane already holds pv and slot
        f32x4 pov;
        if (k == slot) {
            const f32x4* cp4 = (const f32x4*)camera_pose;
            pov = cp4[r4];
        } else {
            pov = pv;
        }
        __builtin_nontemporal_store(pov, &poses_out[pbase + t]);
    }

    __syncthreads();
    const int slot = s_slot;

    const size_t base = (size_t)obj * (KSLOTS * DFEAT / 4);  // 512 f4 per object

    // pass 1: rows 0..3 (row index uniform per wave)
    {
        const int k = t >> 6;
        f32x4 v;
        if (k == slot) v = feat;
        else           v = __builtin_nontemporal_load(&memory[base + t]);
        __builtin_nontemporal_store(v, &mem_out[base + t]);
    }
    // pass 2: rows 4..7
    {
        const int k = 4 + (t >> 6);
        f32x4 v;
        if (k == slot) v = feat;
        else           v = __builtin_nontemporal_load(&memory[base + 256 + t]);
        __builtin_nontemporal_store(v, &mem_out[base + 256 + t]);
    }
}

extern "C" void kernel_launch(void* const* d_in, const int* in_sizes, int n_in,
                              void* d_out, int out_size, void* d_ws, size_t ws_size,
                              hipStream_t stream) {
    const float*         memory        = (const float*)d_in[0];
    const float*         capture_poses = (const float*)d_in[1];
    const unsigned char* slot_filled   = (const unsigned char*)d_in[2];
    const int*           slot_count    = (const int*)d_in[3];
    const int*           object_indices= (const int*)d_in[4];
    const float*         features      = (const float*)d_in[5];
    const float*         camera_pose   = (const float*)d_in[6];
    const int M = in_sizes[4];

    float* out = (float*)d_out;
    float* mem_out    = out;
    float* poses_out  = out + (size_t)MAXOBJ * KSLOTS * DFEAT;                  // 134217728
    float* filled_out = poses_out + (size_t)MAXOBJ * KSLOTS * 16;               // +8388608
    float* count_out  = filled_out + (size_t)MAXOBJ * KSLOTS;                   // +524288

    int* srcs = (int*)d_ws;

    const int B = 256;

    // Unique indices: if M == MAXOBJ the scatter writes every entry -> skip init.
    if (M < MAXOBJ) {
        init_srcs_kernel<<<(MAXOBJ + B - 1) / B, B, 0, stream>>>(srcs, MAXOBJ);
    }
    scatter_srcs_kernel<<<(M + B - 1) / B, B, 0, stream>>>(object_indices, srcs, M);

    fused_kernel<<<MAXOBJ, B, 0, stream>>>(
        (const f32x4*)memory, (const f32x4*)features,
        (const f32x4*)capture_poses, camera_pose,
        slot_filled, slot_count, srcs,
        (f32x4*)mem_out, (f32x4*)poses_out, filled_out, count_out);
}

// Round 4
// 184.117 us; speedup vs baseline: 1.1905x; 1.0357x over previous
//
#include <hip/hip_runtime.h>

#define MAXOBJ 65536
#define KSLOTS 8
#define DFEAT 256

typedef float f32x4 __attribute__((ext_vector_type(4)));

// ws layout (only used when M < MAXOBJ): [0, MAXOBJ) ints: src row or -1

__global__ void init_srcs_kernel(int* __restrict__ srcs, int n) {
    int i = blockIdx.x * blockDim.x + threadIdx.x;
    if (i < n) srcs[i] = -1;
}

__global__ void scatter_srcs_kernel(const int* __restrict__ object_indices,
                                    int* __restrict__ srcs, int M) {
    int m = blockIdx.x * blockDim.x + threadIdx.x;
    if (m < M) srcs[object_indices[m]] = m;
}

// One block (256 threads) = one object.
// DIRECT=true (M == MAXOBJ, unique indices => bijection): block b handles
//   obj = object_indices[b], src = b. Single dispatch, no srcs table.
// DIRECT=false: block b handles obj = b, src = srcs[b] (or -1: untouched).
//
// Wave 0 lanes 0..31: load the 8 stored poses (4 lanes x f32x4 rows each),
// compute the 8 pose deltas (4-lane shuffle reduce), argmin over k (3x
// shfl_xor, lowest-k tie-break == jnp.argmin first-min), derive the target
// slot, write poses_out / filled_out / count_out, broadcast slot via LDS.
// All 256 threads then stream-copy the 8x256-float feature rows with the
// chosen row replaced by features[src]. Control data is block-uniform ->
// scalar loads, wave-uniform branches.
template <bool DIRECT>
__global__ void fused_kernel(const f32x4* __restrict__ memory,
                             const f32x4* __restrict__ features,
                             const f32x4* __restrict__ capture_poses,
                             const float* __restrict__ camera_pose,
                             const unsigned char* __restrict__ slot_filled,
                             const int* __restrict__ slot_count,
                             const int* __restrict__ object_indices,
                             const int* __restrict__ srcs,
                             f32x4* __restrict__ mem_out,
                             f32x4* __restrict__ poses_out,
                             float* __restrict__ filled_out,
                             float* __restrict__ count_out) {
    const int t = threadIdx.x;
    int obj, src;
    if (DIRECT) {
        obj = object_indices[blockIdx.x];  // uniform -> s_load
        src = blockIdx.x;
    } else {
        obj = blockIdx.x;
        src = srcs[obj];                   // uniform -> s_load
    }
    const int d4 = t & 63;

    // Issue the features-row load early; latency hides under pose work.
    f32x4 feat = {0.f, 0.f, 0.f, 0.f};
    if (DIRECT || src >= 0) feat = features[(size_t)src * (DFEAT / 4) + d4];

    __shared__ int s_slot;

    if (t < 32) {
        const int k  = t >> 2;   // pose 0..7
        const int r4 = t & 3;    // row of the 4x4
        const size_t pbase = (size_t)obj * (KSLOTS * 16 / 4);
        f32x4 pv = capture_poses[pbase + t];

        // camera pose rows (uniform scalar loads)
        float Rc00 = camera_pose[0],  Rc01 = camera_pose[1],  Rc02 = camera_pose[2];
        float Rc10 = camera_pose[4],  Rc11 = camera_pose[5],  Rc12 = camera_pose[6];
        float Rc20 = camera_pose[8],  Rc21 = camera_pose[9],  Rc22 = camera_pose[10];
        float tc0 = camera_pose[3], tc1 = camera_pose[7], tc2 = camera_pose[11];

        // per-lane partial: stored-rotation row l = r4 (cols pv.x..z),
        // stored translation element = pv.w
        float rot_part = 0.f, tr_part = 0.f;
        if (r4 < 3) {
            float v0 = Rc00 * pv.x + Rc01 * pv.y + Rc02 * pv.z - (r4 == 0 ? 1.f : 0.f);
            float v1 = Rc10 * pv.x + Rc11 * pv.y + Rc12 * pv.z - (r4 == 1 ? 1.f : 0.f);
            float v2 = Rc20 * pv.x + Rc21 * pv.y + Rc22 * pv.z - (r4 == 2 ? 1.f : 0.f);
            rot_part = v0 * v0 + v1 * v1 + v2 * v2;
            float tcur = (r4 == 0) ? tc0 : (r4 == 1) ? tc1 : tc2;
            float dt = tcur - pv.w;
            tr_part = dt * dt;
        }
        // reduce over the 4 lanes of this pose group
        rot_part += __shfl_xor(rot_part, 1);
        tr_part  += __shfl_xor(tr_part, 1);
        rot_part += __shfl_xor(rot_part, 2);
        tr_part  += __shfl_xor(tr_part, 2);
        float delta = sqrtf(rot_part) + sqrtf(tr_part);

        // argmin over the 8 pose groups (lanes differ only in bits 2..4)
        int bestk = k;
        float bestd = delta;
#pragma unroll
        for (int mask = 4; mask <= 16; mask <<= 1) {
            float od = __shfl_xor(bestd, mask);
            int   ok = __shfl_xor(bestk, mask);
            if (od < bestd || (od == bestd && ok < bestk)) { bestd = od; bestk = ok; }
        }

        const int cnt = slot_count[obj];   // uniform -> s_load
        const int fill = (cnt < KSLOTS) ? 1 : 0;
        const int touched = DIRECT || src >= 0;
        const int slot = touched ? (fill ? cnt : bestk) : -1;

        if (t == 0) {
            s_slot = slot;
            count_out[obj] = (float)(cnt + (touched ? fill : 0));
        }
        if (t < KSLOTS) {
            int was = slot_filled[obj * KSLOTS + t] != 0;
            filled_out[obj * KSLOTS + t] = (was || t == slot) ? 1.0f : 0.0f;
        }
        // pose copy: this lane already holds pv and slot
        f32x4 pov;
        if (k == slot) {
            const f32x4* cp4 = (const f32x4*)camera_pose;
            pov = cp4[r4];
        } else {
            pov = pv;
        }
        __builtin_nontemporal_store(pov, &poses_out[pbase + t]);
    }

    __syncthreads();
    const int slot = s_slot;

    const size_t base = (size_t)obj * (KSLOTS * DFEAT / 4);  // 512 f4 per object

    // pass 1: rows 0..3 (row index uniform per wave)
    {
        const int k = t >> 6;
        f32x4 v;
        if (k == slot) v = feat;
        else           v = __builtin_nontemporal_load(&memory[base + t]);
        __builtin_nontemporal_store(v, &mem_out[base + t]);
    }
    // pass 2: rows 4..7
    {
        const int k = 4 + (t >> 6);
        f32x4 v;
        if (k == slot) v = feat;
        else           v = __builtin_nontemporal_load(&memory[base + 256 + t]);
        __builtin_nontemporal_store(v, &mem_out[base + 256 + t]);
    }
}

extern "C" void kernel_launch(void* const* d_in, const int* in_sizes, int n_in,
                              void* d_out, int out_size, void* d_ws, size_t ws_size,
                              hipStream_t stream) {
    const float*         memory        = (const float*)d_in[0];
    const float*         capture_poses = (const float*)d_in[1];
    const unsigned char* slot_filled   = (const unsigned char*)d_in[2];
    const int*           slot_count    = (const int*)d_in[3];
    const int*           object_indices= (const int*)d_in[4];
    const float*         features      = (const float*)d_in[5];
    const float*         camera_pose   = (const float*)d_in[6];
    const int M = in_sizes[4];

    float* out = (float*)d_out;
    float* mem_out    = out;
    float* poses_out  = out + (size_t)MAXOBJ * KSLOTS * DFEAT;                  // 134217728
    float* filled_out = poses_out + (size_t)MAXOBJ * KSLOTS * 16;               // +8388608
    float* count_out  = filled_out + (size_t)MAXOBJ * KSLOTS;                   // +524288

    const int B = 256;

    if (M == MAXOBJ) {
        // Unique indices + M == MAXOBJ => bijection: every object handled by
        // exactly one block. Single dispatch, no scatter table.
        fused_kernel<true><<<MAXOBJ, B, 0, stream>>>(
            (const f32x4*)memory, (const f32x4*)features,
            (const f32x4*)capture_poses, camera_pose,
            slot_filled, slot_count, object_indices, nullptr,
            (f32x4*)mem_out, (f32x4*)poses_out, filled_out, count_out);
    } else {
        int* srcs = (int*)d_ws;
        init_srcs_kernel<<<(MAXOBJ + B - 1) / B, B, 0, stream>>>(srcs, MAXOBJ);
        scatter_srcs_kernel<<<(M + B - 1) / B, B, 0, stream>>>(object_indices, srcs, M);
        fused_kernel<false><<<MAXOBJ, B, 0, stream>>>(
            (const f32x4*)memory, (const f32x4*)features,
            (const f32x4*)capture_poses, camera_pose,
            slot_filled, slot_count, nullptr, srcs,
            (f32x4*)mem_out, (f32x4*)poses_out, filled_out, count_out);
    }
}